// Round 14
// baseline (112.880 us; speedup 1.0000x reference)
//
#include <hip/hip_runtime.h>
#include <hip/hip_fp16.h>

#define B_    2
#define T_    400
#define NCH_  8
#define NBIN_ 512
#define NBAND_ 40
#define NPV_  64

using half8   = __attribute__((ext_vector_type(8))) _Float16;
using float4v = __attribute__((ext_vector_type(4))) float;

// pack two floats into fp16 pair dword (lo=x, hi=y), RNE
static __device__ inline unsigned pkhf(float x, float y) {
  __half2 h = __float22half2_rn(make_float2(x, y));
  return __builtin_bit_cast(unsigned, h);
}
static __device__ inline unsigned rot16(unsigned u) {
  return (u >> 16) | (u << 16);
}
// packed complex multiply a = v_i * conj(v_j); dwords are (lo=re, hi=im)
static __device__ inline unsigned cmulc(unsigned viu, unsigned vju) {
  __half2 Vi = __builtin_bit_cast(__half2, viu);
  __half2 Vj = __builtin_bit_cast(__half2, vju);
  __half2 P1 = __hmul2(Vi, __low2half2(Vj));
  __half2 Qi = __lowhigh2highlow(Vi);
  unsigned tn = __builtin_bit_cast(unsigned, __high2half2(Vj)) ^ 0x80000000u;
  __half2 a  = __hfma2(Qi, __builtin_bit_cast(__half2, tn), P1);
  return __builtin_bit_cast(unsigned, a);
}
// async global->LDS DMA, 16 B per lane (dest = wave-uniform base + lane*16)
static __device__ inline void gld_lds16(const uint4* g, uint4* l) {
  auto* lds_ptr = reinterpret_cast<__attribute__((address_space(3))) uint4*>(
      reinterpret_cast<uintptr_t>(l));
  auto* g_ptr = reinterpret_cast<const __attribute__((address_space(1))) uint4*>(
      reinterpret_cast<uintptr_t>(g));
  __builtin_amdgcn_global_load_lds(g_ptr, lds_ptr, 16, 0, 0);
}

// ws layout (bytes):
//   [0..159]              : dsinv[40] floats
//   [1024, 1024+98304)    : band B-frags (fp16 pairs), s-major, stored once:
//                           F=(s*3+n)*64+lane, uint4; dword t = (bmr, bmi) at
//                           f = s*16 + (lane>>4)*4 + t, k = n*16 + (lane&15)
//   [197632, 197632+16384): epi B-frags (fp16): E=(nt*4+ks)*64+lane, uint4
__global__ __launch_bounds__(256) void pv_prep(
    const float* __restrict__ bmr, const float* __restrict__ bmi,
    const float* __restrict__ c2pr, const float* __restrict__ c2pi,
    float* __restrict__ ws)
{
  const int tid = threadIdx.x;
  const int blk = blockIdx.x;
  if (blk == 0) {
    __shared__ float sds[256];
    int k = tid & 63, part = tid >> 6;
    float s = 0.f;
    if (k < NBAND_) {
      const float* col = bmr + k;
      #pragma unroll 16
      for (int f = part * 128; f < part * 128 + 128; f++) s += col[f * 40];
    }
    sds[tid] = s;
    __syncthreads();
    if (tid < NBAND_) {
      float t = sds[tid] + sds[tid + 64] + sds[tid + 128] + sds[tid + 192];
      ws[tid] = 1.0f / fmaxf(t, 1e-20f);
    }
  } else if (blk <= 24) {
    int F = (blk - 1) * 256 + tid;     // 0..6143
    int l = F & 63;
    int fid = F >> 6;                  // s*3 + n
    int s5 = fid / 3;
    int n = fid - s5 * 3;
    int k = n * 16 + (l & 15);
    int quad = l >> 4;
    unsigned dw[4];
    #pragma unroll
    for (int t2 = 0; t2 < 4; t2++) {
      float v0 = 0.f, v1 = 0.f;
      if (k < NBAND_) {
        int f = s5 * 16 + quad * 4 + t2;
        v0 = bmr[f * 40 + k]; v1 = bmi[f * 40 + k];
      }
      dw[t2] = pkhf(v0, v1);
    }
    ((uint4*)((char*)ws + 1024))[F] = make_uint4(dw[0], dw[1], dw[2], dw[3]);
  } else {
    int F2 = (blk - 25) * 256 + tid;   // 0..1023
    int lane = F2 & 63, E = F2 >> 6;
    int nt = E >> 2, ks = E & 3;
    int n = lane & 15, quad = lane >> 4;
    int p = nt * 16 + n;
    unsigned dw[4];
    #pragma unroll
    for (int t2 = 0; t2 < 4; t2++) {
      int c = ks * 16 + quad * 4 + t2;
      dw[t2] = pkhf(c2pr[p * 64 + c], -c2pi[p * 64 + c]);
    }
    ((uint4*)((char*)ws + 197632))[E * 64 + lane] = make_uint4(dw[0], dw[1], dw[2], dw[3]);
  }
}

// ONE frame per block, 800 blocks. Phase A: two-pass through LDS (r13,
// verified). K-loop B-delivery CHANGED (single variable this round):
// double-buffered global_load_lds staging of the B-panel — ONE copy per
// block instead of 4 redundant per-wave register streams (384->96 KB/block
// through L1), zero VGPR round-trip, r0's verified stage layout:
//   stage st holds K-steps s=st*4+q; bst[buf][(q*3+n)*64+lane] uint4.
// Loop order: issue stage st+1 DMA -> compute stage st -> barrier (DMA had
// the 4-step compute to land; barrier drains residual + guards buf reuse).
// LDS 48 KB total: raw 32 KB @0 (dead after pass 2; bst[2][768]=24 KB
// overlays it), vsh 16 KB @8192dw. 3 blocks/CU (grid-limited).
__global__ __launch_bounds__(256, 3) void pv_main(
    const float* __restrict__ br, const float* __restrict__ bi,
    const float* __restrict__ ws, float* __restrict__ out)
{
  __shared__ __align__(16) unsigned smem[12288];

  const int bt  = blockIdx.x;          // 0..799 = b*T + t
  const int tid = threadIdx.x;

  const int mt   = tid >> 6;       // wave id = M-tile
  const int lane = tid & 63;
  const int m16  = lane & 15;
  const int quad = lane >> 4;
  const int p    = mt * 16 + m16;
  const int ich  = p >> 3, jch = p & 7;
  const uint4* BF0 = (const uint4*)((const char*)ws + 1024);
  unsigned* vsh = smem + 8192;

  // ---- phase A pass 1: stage frame into LDS (aligned, coalesced) ----
  {
    const float4* gr4 = (const float4*)(br + (size_t)bt * (NCH_ * NBIN_));
    const float4* gi4 = (const float4*)(bi + (size_t)bt * (NCH_ * NBIN_));
    float4* lr4 = (float4*)smem;             // raw_re[8][512] as float4[1024]
    float4* li4 = (float4*)(smem + 4096);    // raw_im
    #pragma unroll
    for (int it = 0; it < 4; it++) {
      lr4[it * 256 + tid] = gr4[it * 256 + tid];
      li4[it * 256 + tid] = gi4[it * 256 + tid];
    }
  }
  __syncthreads();

  // ---- phase A pass 2: verbatim reference math, inputs from LDS ----
  {
    const float* rr = (const float*)smem;           // raw_re[c*512 + f]
    const float* ri = (const float*)(smem + 4096);  // raw_im
    #pragma unroll
    for (int fs = 0; fs < 2; fs++) {
      const int f = fs * 256 + tid;
      const int fm = (f == 0) ? 0 : ((f == 511) ? 509 : f - 1);
      const int fp = (f == 0) ? 2 : ((f == 511) ? 511 : f + 1);
      float tr = 0.f;
      float t1[8], t2[8];
      #pragma unroll
      for (int c = 0; c < 8; c++) {
        const float* cr = rr + c * 512;
        const float* ci = ri + c * 512;
        float xr = cr[f],   xi = ci[f];
        float xrm = cr[fm], xim = ci[fm];
        float xrp = cr[fp], xip = ci[fp];
        tr = fmaf(xr, xr, tr); tr = fmaf(xi, xi, tr);
        float Gr = fmaf(xrm, xrp,  xim * xip);
        float Gi = fmaf(xrm, xip, -(xim * xrp));
        float am = fmaxf(fmaxf(fabsf(Gr), fabsf(Gi)), 1e-30f);
        float rc = __builtin_amdgcn_rcpf(am);
        float q1 = Gr * rc, q2 = Gi * rc;
        float n2 = fmaf(q1, q1, q2 * q2);
        float rn = __builtin_amdgcn_rsqf(n2);
        bool ok = n2 > 0.f;
        float ur = ok ? q1 * rn : 1.f;
        float ui = ok ? q2 * rn : 0.f;
        float mg = __builtin_amdgcn_sqrtf(fmaf(xr, xr, xi * xi));
        t1[c] = mg * ur; t2[c] = mg * ui;
      }
      float scv = __builtin_amdgcn_rsqf(fmaxf(tr, 1e-20f));
      const int fc = f >> 2, fl = f & 3;
      #pragma unroll
      for (int c = 0; c < 8; c++)
        vsh[c * 512 + ((fc ^ c) << 2) + fl] = pkhf(t1[c] * scv, t2[c] * scv);
    }
  }
  __syncthreads();               // vsh ready AND raw region dead

  // ---- band GEMM: 8 stages x 4 K-steps; B via global_load_lds dbuf ----
  uint4* bst = (uint4*)smem;     // [2][768] overlays dead raw region (24 KB)
  {                              // stage 0 DMA + drain
    const uint4* g = BF0 + tid;
    uint4* l = bst + tid;
    gld_lds16(g, l);
    gld_lds16(g + 256, l + 256);
    gld_lds16(g + 512, l + 512);
  }
  __syncthreads();               // stage 0 landed

  float4v acc[6];                // [0..2]=real cols, [3..5]=imag cols
  #pragma unroll
  for (int g = 0; g < 6; g++) acc[g] = (float4v){0.f, 0.f, 0.f, 0.f};

  for (int st = 0; st < 8; st++) {
    if (st < 7) {                // DMA next stage into the other buffer
      const uint4* g = BF0 + (st + 1) * 768 + tid;
      uint4* l = bst + ((st + 1) & 1) * 768 + tid;
      gld_lds16(g, l);
      gld_lds16(g + 256, l + 256);
      gld_lds16(g + 512, l + 512);
    }
    const uint4* bb = bst + (st & 1) * 768;
    #pragma unroll
    for (int q = 0; q < 4; q++) {
      const int s = st * 4 + q;
      const int sc = s * 4 + quad;           // chunk index pre-swizzle
      uint4 cb0 = bb[(q * 3 + 0) * 64 + lane];
      uint4 cb1 = bb[(q * 3 + 1) * 64 + lane];
      uint4 cb2 = bb[(q * 3 + 2) * 64 + lane];
      half8 b0 = __builtin_bit_cast(half8, cb0);
      half8 b1 = __builtin_bit_cast(half8, cb1);
      half8 b2 = __builtin_bit_cast(half8, cb2);
      const uint4* vb = (const uint4*)vsh;
      uint4 av = vb[ich * 128 + (sc ^ ich)];
      uint4 bv = vb[jch * 128 + (sc ^ jch)];
      unsigned a0 = cmulc(av.x, bv.x);
      unsigned a1 = cmulc(av.y, bv.y);
      unsigned a2 = cmulc(av.z, bv.z);
      unsigned a3 = cmulc(av.w, bv.w);
      uint4 au1 = make_uint4(a0 ^ 0x80000000u, a1 ^ 0x80000000u,
                             a2 ^ 0x80000000u, a3 ^ 0x80000000u); // (ar, -ai)
      uint4 au2 = make_uint4(rot16(a0), rot16(a1),
                             rot16(a2), rot16(a3));               // (ai, ar)
      half8 af1 = __builtin_bit_cast(half8, au1);
      half8 af2 = __builtin_bit_cast(half8, au2);
      acc[0] = __builtin_amdgcn_mfma_f32_16x16x32_f16(af1, b0, acc[0], 0, 0, 0);
      acc[3] = __builtin_amdgcn_mfma_f32_16x16x32_f16(af2, b0, acc[3], 0, 0, 0);
      acc[1] = __builtin_amdgcn_mfma_f32_16x16x32_f16(af1, b1, acc[1], 0, 0, 0);
      acc[4] = __builtin_amdgcn_mfma_f32_16x16x32_f16(af2, b1, acc[4], 0, 0, 0);
      acc[2] = __builtin_amdgcn_mfma_f32_16x16x32_f16(af1, b2, acc[2], 0, 0, 0);
      acc[5] = __builtin_amdgcn_mfma_f32_16x16x32_f16(af2, b2, acc[5], 0, 0, 0);
    }
    __syncthreads();             // next-stage DMA landed; guards buf reuse
  }

  // ---- epilogue GEMM: pv[k][p] = Re(sum_c c2p[p][c]*bc[k][c]) ----
  const uint4* EF = ((const uint4*)((const char*)ws + 197632)) + (mt * 4) * 64 + lane;
  uint4 eb[4];
  #pragma unroll
  for (int ks = 0; ks < 4; ks++) eb[ks] = EF[ks * 64];

  {
    unsigned* bcsh = smem;             // [48][68] fp16-pair, overlays bst/raw
    #pragma unroll
    for (int n = 0; n < 3; n++) {
      uint4 w4 = make_uint4(pkhf(acc[n][0], acc[n+3][0]),
                            pkhf(acc[n][1], acc[n+3][1]),
                            pkhf(acc[n][2], acc[n+3][2]),
                            pkhf(acc[n][3], acc[n+3][3]));
      *(uint4*)(bcsh + (n * 16 + m16) * 68 + mt * 16 + quad * 4) = w4;
    }
  }
  __syncthreads();

  const float4* wsd = (const float4*)ws;   // dsinv[40]
  {
    const unsigned* bcsh = smem;
    float4v eacc[3];
    #pragma unroll
    for (int kt = 0; kt < 3; kt++) eacc[kt] = (float4v){0.f, 0.f, 0.f, 0.f};
    #pragma unroll
    for (int ks = 0; ks < 4; ks++) {
      half8 bfr = __builtin_bit_cast(half8, eb[ks]);
      #pragma unroll
      for (int kt = 0; kt < 3; kt++) {
        uint4 a4 = *(const uint4*)(bcsh + (kt * 16 + m16) * 68 + ks * 16 + quad * 4);
        half8 afr = __builtin_bit_cast(half8, a4);
        eacc[kt] = __builtin_amdgcn_mfma_f32_16x16x32_f16(afr, bfr, eacc[kt], 0, 0, 0);
      }
    }
    float* op = out + (size_t)bt * (NBAND_ * NPV_);
    #pragma unroll
    for (int kt = 0; kt < 3; kt++) {
      float4 dv = wsd[kt * 4 + quad];
      float dva[4] = {dv.x, dv.y, dv.z, dv.w};
      #pragma unroll
      for (int r = 0; r < 4; r++) {
        int k = kt * 16 + quad * 4 + r;
        if (k < NBAND_)
          op[k * 64 + mt * 16 + m16] = eacc[kt][r] * dva[r];
      }
    }
  }
}

// ---------------- IIR: chunked scan, chunk=25, 160 blocks x 512 thr ----------------
// block = (b, k, ph); ph in {0,1} selects p-half [ph*32, ph*32+32).
// thread = (chunk c in [0,16), pl in [0,32)). A wave covers 32 consecutive p
// of chunks c and c+1 -> each load/store is two contiguous 128-B segments
// (fully coalesced). Same verified scan math with A = a^25. gsh[16][32].
__global__ __launch_bounds__(512) void pv_iir4(float* __restrict__ z,
                                               const float* __restrict__ tau)
{
  __shared__ float gsh[16][32];
  const int ph = blockIdx.x & 1;
  const int bk = blockIdx.x >> 1;            // 0..79 = b*40+k
  const int k = bk % NBAND_;
  const int b = bk / NBAND_;
  const float a  = tau[k];
  const float om = 1.0f - a;
  const int c  = threadIdx.x >> 5;           // chunk 0..15
  const int pl = threadIdx.x & 31;
  const int p  = ph * 32 + pl;
  const size_t stride = (size_t)NBAND_ * 64;
  size_t idx0 = (size_t)b * (T_ * NBAND_ * 64) + (size_t)(c * 25) * stride + k * 64 + p;

  float y[25];
  float accv = 0.f;
  #pragma unroll
  for (int i = 0; i < 25; i++) {
    float v = z[idx0 + (size_t)i * stride];
    accv = fmaf(a, accv, om * v);
    y[i] = accv;
  }
  gsh[c][pl] = accv;
  __syncthreads();
  float a2 = a * a, a4 = a2 * a2, a8 = a4 * a4, a16 = a8 * a8;
  float A = a16 * a8 * a;                    // a^25
  float H = 0.f;
  #pragma unroll
  for (int d = 0; d < 15; d++) {
    float g = gsh[d][pl];
    H = (d < c) ? fmaf(A, H, g) : H;
  }
  float wp = a;
  #pragma unroll
  for (int i = 0; i < 25; i++) {
    z[idx0 + (size_t)i * stride] = fmaf(wp, H, y[i]);
    wp *= a;
  }
}

extern "C" void kernel_launch(void* const* d_in, const int* in_sizes, int n_in,
                              void* d_out, int out_size, void* d_ws, size_t ws_size,
                              hipStream_t stream)
{
  const float* br   = (const float*)d_in[0];
  const float* bi   = (const float*)d_in[1];
  const float* bmr  = (const float*)d_in[2];
  const float* bmi  = (const float*)d_in[3];
  const float* c2pr = (const float*)d_in[4];
  const float* c2pi = (const float*)d_in[5];
  const float* tau  = (const float*)d_in[6];
  float* out = (float*)d_out;
  float* ws  = (float*)d_ws;

  hipLaunchKernelGGL(pv_prep, dim3(29), dim3(256), 0, stream,
                     bmr, bmi, c2pr, c2pi, ws);
  hipLaunchKernelGGL(pv_main, dim3(B_ * T_), dim3(256), 0, stream,
                     br, bi, ws, out);
  hipLaunchKernelGGL(pv_iir4, dim3(B_ * NBAND_ * 2), dim3(512), 0, stream,
                     out, tau);
}

// Round 15
// 109.898 us; speedup vs baseline: 1.0271x; 1.0271x over previous
//
#include <hip/hip_runtime.h>
#include <hip/hip_fp16.h>

#define B_    2
#define T_    400
#define NCH_  8
#define NBIN_ 512
#define NBAND_ 40
#define NPV_  64

using half8   = __attribute__((ext_vector_type(8))) _Float16;
using float4v = __attribute__((ext_vector_type(4))) float;

// pack two floats into fp16 pair dword (lo=x, hi=y), RNE
static __device__ inline unsigned pkhf(float x, float y) {
  __half2 h = __float22half2_rn(make_float2(x, y));
  return __builtin_bit_cast(unsigned, h);
}
static __device__ inline unsigned rot16(unsigned u) {
  return (u >> 16) | (u << 16);
}
// packed complex multiply a = v_i * conj(v_j); dwords are (lo=re, hi=im)
static __device__ inline unsigned cmulc(unsigned viu, unsigned vju) {
  __half2 Vi = __builtin_bit_cast(__half2, viu);
  __half2 Vj = __builtin_bit_cast(__half2, vju);
  __half2 P1 = __hmul2(Vi, __low2half2(Vj));
  __half2 Qi = __lowhigh2highlow(Vi);
  unsigned tn = __builtin_bit_cast(unsigned, __high2half2(Vj)) ^ 0x80000000u;
  __half2 a  = __hfma2(Qi, __builtin_bit_cast(__half2, tn), P1);
  return __builtin_bit_cast(unsigned, a);
}

// ws layout (bytes):
//   [0..159]              : dsinv[40] floats
//   [1024, 1024+98304)    : band B-frags (fp16 pairs), s-major, stored once:
//                           F=(s*3+n)*64+lane, uint4; dword t = (bmr, bmi) at
//                           f = s*16 + (lane>>4)*4 + t, k = n*16 + (lane&15)
//   [197632, 197632+16384): epi B-frags (fp16): E=(nt*4+ks)*64+lane, uint4
__global__ __launch_bounds__(256) void pv_prep(
    const float* __restrict__ bmr, const float* __restrict__ bmi,
    const float* __restrict__ c2pr, const float* __restrict__ c2pi,
    float* __restrict__ ws)
{
  const int tid = threadIdx.x;
  const int blk = blockIdx.x;
  if (blk == 0) {
    __shared__ float sds[256];
    int k = tid & 63, part = tid >> 6;
    float s = 0.f;
    if (k < NBAND_) {
      const float* col = bmr + k;
      #pragma unroll 16
      for (int f = part * 128; f < part * 128 + 128; f++) s += col[f * 40];
    }
    sds[tid] = s;
    __syncthreads();
    if (tid < NBAND_) {
      float t = sds[tid] + sds[tid + 64] + sds[tid + 128] + sds[tid + 192];
      ws[tid] = 1.0f / fmaxf(t, 1e-20f);
    }
  } else if (blk <= 24) {
    int F = (blk - 1) * 256 + tid;     // 0..6143
    int l = F & 63;
    int fid = F >> 6;                  // s*3 + n
    int s5 = fid / 3;
    int n = fid - s5 * 3;
    int k = n * 16 + (l & 15);
    int quad = l >> 4;
    unsigned dw[4];
    #pragma unroll
    for (int t2 = 0; t2 < 4; t2++) {
      float v0 = 0.f, v1 = 0.f;
      if (k < NBAND_) {
        int f = s5 * 16 + quad * 4 + t2;
        v0 = bmr[f * 40 + k]; v1 = bmi[f * 40 + k];
      }
      dw[t2] = pkhf(v0, v1);
    }
    ((uint4*)((char*)ws + 1024))[F] = make_uint4(dw[0], dw[1], dw[2], dw[3]);
  } else {
    int F2 = (blk - 25) * 256 + tid;   // 0..1023
    int lane = F2 & 63, E = F2 >> 6;
    int nt = E >> 2, ks = E & 3;
    int n = lane & 15, quad = lane >> 4;
    int p = nt * 16 + n;
    unsigned dw[4];
    #pragma unroll
    for (int t2 = 0; t2 < 4; t2++) {
      int c = ks * 16 + quad * 4 + t2;
      dw[t2] = pkhf(c2pr[p * 64 + c], -c2pi[p * 64 + c]);
    }
    ((uint4*)((char*)ws + 197632))[E * 64 + lane] = make_uint4(dw[0], dw[1], dw[2], dw[3]);
  }
}

// ONE frame per block, 800 blocks. Phase A is TWO-PASS through LDS:
//   pass 1: stage the whole 32 KB frame (re+im) with ALIGNED, fully-coalesced
//           float4 loads (frame base is 16 KB-aligned; 8 float4/thread/array)
//   pass 2: verbatim reference math (f = fs*256+tid, clamped fm/fp)
//           reading from LDS (4-B access free) -- no edge special-case.
// K-loop: 2-deep register prefetch of B-frags (L2-hot).
// LDS 48 KB: raw_re[8][512]f32 @0, raw_im @4096dw, vsh @8192dw -> 3 blocks/CU.
//   vsh uint[8][512] (XOR-chunk swizzle (c,f): c*512+(((f>>2)^c)<<2)+(f&3))
//   epilogue: bcsh uint[48][68] overlays raw_re (dead after pass 2)
// [VERIFIED BEST: 107.77us total — rounds 11-13]
__global__ __launch_bounds__(256, 3) void pv_main(
    const float* __restrict__ br, const float* __restrict__ bi,
    const float* __restrict__ ws, float* __restrict__ out)
{
  __shared__ __align__(16) unsigned smem[12288];

  const int bt  = blockIdx.x;          // 0..799 = b*T + t
  const int tid = threadIdx.x;

  const int mt   = tid >> 6;       // wave id = M-tile
  const int lane = tid & 63;
  const int m16  = lane & 15;
  const int quad = lane >> 4;
  const int p    = mt * 16 + m16;
  const int ich  = p >> 3, jch = p & 7;
  const uint4* BF0 = (const uint4*)((const char*)ws + 1024);
  unsigned* vsh = smem + 8192;

  // ---- phase A pass 1: stage frame into LDS (aligned, coalesced) ----
  {
    const float4* gr4 = (const float4*)(br + (size_t)bt * (NCH_ * NBIN_));
    const float4* gi4 = (const float4*)(bi + (size_t)bt * (NCH_ * NBIN_));
    float4* lr4 = (float4*)smem;             // raw_re[8][512] as float4[1024]
    float4* li4 = (float4*)(smem + 4096);    // raw_im
    #pragma unroll
    for (int it = 0; it < 4; it++) {
      lr4[it * 256 + tid] = gr4[it * 256 + tid];
      li4[it * 256 + tid] = gi4[it * 256 + tid];
    }
  }
  __syncthreads();

  // ---- phase A pass 2: verbatim reference math, inputs from LDS ----
  {
    const float* rr = (const float*)smem;           // raw_re[c*512 + f]
    const float* ri = (const float*)(smem + 4096);  // raw_im
    #pragma unroll
    for (int fs = 0; fs < 2; fs++) {
      const int f = fs * 256 + tid;
      const int fm = (f == 0) ? 0 : ((f == 511) ? 509 : f - 1);
      const int fp = (f == 0) ? 2 : ((f == 511) ? 511 : f + 1);
      float tr = 0.f;
      float t1[8], t2[8];
      #pragma unroll
      for (int c = 0; c < 8; c++) {
        const float* cr = rr + c * 512;
        const float* ci = ri + c * 512;
        float xr = cr[f],   xi = ci[f];
        float xrm = cr[fm], xim = ci[fm];
        float xrp = cr[fp], xip = ci[fp];
        tr = fmaf(xr, xr, tr); tr = fmaf(xi, xi, tr);
        float Gr = fmaf(xrm, xrp,  xim * xip);
        float Gi = fmaf(xrm, xip, -(xim * xrp));
        float am = fmaxf(fmaxf(fabsf(Gr), fabsf(Gi)), 1e-30f);
        float rc = __builtin_amdgcn_rcpf(am);
        float q1 = Gr * rc, q2 = Gi * rc;
        float n2 = fmaf(q1, q1, q2 * q2);
        float rn = __builtin_amdgcn_rsqf(n2);
        bool ok = n2 > 0.f;
        float ur = ok ? q1 * rn : 1.f;
        float ui = ok ? q2 * rn : 0.f;
        float mg = __builtin_amdgcn_sqrtf(fmaf(xr, xr, xi * xi));
        t1[c] = mg * ur; t2[c] = mg * ui;
      }
      float scv = __builtin_amdgcn_rsqf(fmaxf(tr, 1e-20f));
      const int fc = f >> 2, fl = f & 3;
      #pragma unroll
      for (int c = 0; c < 8; c++)
        vsh[c * 512 + ((fc ^ c) << 2) + fl] = pkhf(t1[c] * scv, t2[c] * scv);
    }
  }
  __syncthreads();               // vsh ready; K-loop below is barrier-free

  // ---- band GEMM: 32 K-steps; B-frags from L2 via 2-deep reg prefetch ----
  float4v acc[6];                // [0..2]=real cols, [3..5]=imag cols
  #pragma unroll
  for (int g = 0; g < 6; g++) acc[g] = (float4v){0.f, 0.f, 0.f, 0.f};

  const uint4* Bg = BF0 + lane;
  uint4 pa0 = Bg[0],   pa1 = Bg[64],  pa2 = Bg[128];   // step s
  uint4 pb0 = Bg[192], pb1 = Bg[256], pb2 = Bg[320];   // step s+1
  #pragma unroll 4
  for (int s = 0; s < 32; s++) {
    uint4 cb0 = pa0, cb1 = pa1, cb2 = pa2;
    pa0 = pb0; pa1 = pb1; pa2 = pb2;
    {
      const uint4* nx = Bg + (size_t)(((s + 2) & 31) * 192);
      pb0 = nx[0]; pb1 = nx[64]; pb2 = nx[128];
    }
    const int sc = s * 4 + quad;           // chunk index pre-swizzle
    half8 b0 = __builtin_bit_cast(half8, cb0);
    half8 b1 = __builtin_bit_cast(half8, cb1);
    half8 b2 = __builtin_bit_cast(half8, cb2);
    const uint4* vb = (const uint4*)vsh;
    uint4 av = vb[ich * 128 + (sc ^ ich)];
    uint4 bv = vb[jch * 128 + (sc ^ jch)];
    unsigned a0 = cmulc(av.x, bv.x);
    unsigned a1 = cmulc(av.y, bv.y);
    unsigned a2 = cmulc(av.z, bv.z);
    unsigned a3 = cmulc(av.w, bv.w);
    uint4 au1 = make_uint4(a0 ^ 0x80000000u, a1 ^ 0x80000000u,
                           a2 ^ 0x80000000u, a3 ^ 0x80000000u); // (ar, -ai)
    uint4 au2 = make_uint4(rot16(a0), rot16(a1),
                           rot16(a2), rot16(a3));               // (ai, ar)
    half8 af1 = __builtin_bit_cast(half8, au1);
    half8 af2 = __builtin_bit_cast(half8, au2);
    acc[0] = __builtin_amdgcn_mfma_f32_16x16x32_f16(af1, b0, acc[0], 0, 0, 0);
    acc[3] = __builtin_amdgcn_mfma_f32_16x16x32_f16(af2, b0, acc[3], 0, 0, 0);
    acc[1] = __builtin_amdgcn_mfma_f32_16x16x32_f16(af1, b1, acc[1], 0, 0, 0);
    acc[4] = __builtin_amdgcn_mfma_f32_16x16x32_f16(af2, b1, acc[4], 0, 0, 0);
    acc[2] = __builtin_amdgcn_mfma_f32_16x16x32_f16(af1, b2, acc[2], 0, 0, 0);
    acc[5] = __builtin_amdgcn_mfma_f32_16x16x32_f16(af2, b2, acc[5], 0, 0, 0);
  }
  __syncthreads();               // all waves done with K-loop

  // ---- epilogue GEMM: pv[k][p] = Re(sum_c c2p[p][c]*bc[k][c]) ----
  const uint4* EF = ((const uint4*)((const char*)ws + 197632)) + (mt * 4) * 64 + lane;
  uint4 eb[4];
  #pragma unroll
  for (int ks = 0; ks < 4; ks++) eb[ks] = EF[ks * 64];

  {
    unsigned* bcsh = smem;             // [48][68] fp16-pair, overlays raw_re
    #pragma unroll
    for (int n = 0; n < 3; n++) {
      uint4 w4 = make_uint4(pkhf(acc[n][0], acc[n+3][0]),
                            pkhf(acc[n][1], acc[n+3][1]),
                            pkhf(acc[n][2], acc[n+3][2]),
                            pkhf(acc[n][3], acc[n+3][3]));
      *(uint4*)(bcsh + (n * 16 + m16) * 68 + mt * 16 + quad * 4) = w4;
    }
  }
  __syncthreads();

  const float4* wsd = (const float4*)ws;   // dsinv[40]
  {
    const unsigned* bcsh = smem;
    float4v eacc[3];
    #pragma unroll
    for (int kt = 0; kt < 3; kt++) eacc[kt] = (float4v){0.f, 0.f, 0.f, 0.f};
    #pragma unroll
    for (int ks = 0; ks < 4; ks++) {
      half8 bfr = __builtin_bit_cast(half8, eb[ks]);
      #pragma unroll
      for (int kt = 0; kt < 3; kt++) {
        uint4 a4 = *(const uint4*)(bcsh + (kt * 16 + m16) * 68 + ks * 16 + quad * 4);
        half8 afr = __builtin_bit_cast(half8, a4);
        eacc[kt] = __builtin_amdgcn_mfma_f32_16x16x32_f16(afr, bfr, eacc[kt], 0, 0, 0);
      }
    }
    float* op = out + (size_t)bt * (NBAND_ * NPV_);
    #pragma unroll
    for (int kt = 0; kt < 3; kt++) {
      float4 dv = wsd[kt * 4 + quad];
      float dva[4] = {dv.x, dv.y, dv.z, dv.w};
      #pragma unroll
      for (int r = 0; r < 4; r++) {
        int k = kt * 16 + quad * 4 + r;
        if (k < NBAND_)
          op[k * 64 + mt * 16 + m16] = eacc[kt][r] * dva[r];
      }
    }
  }
}

// ---------------- IIR: chunked scan, chunk=25, 160 blocks x 512 thr ----------------
// block = (b, k, ph); ph in {0,1} selects p-half [ph*32, ph*32+32).
// thread = (chunk c in [0,16), pl in [0,32)). A wave covers 32 consecutive p
// of chunks c and c+1 -> each load/store is two contiguous 128-B segments
// (fully coalesced). Same verified scan math with A = a^25. gsh[16][32].
__global__ __launch_bounds__(512) void pv_iir4(float* __restrict__ z,
                                               const float* __restrict__ tau)
{
  __shared__ float gsh[16][32];
  const int ph = blockIdx.x & 1;
  const int bk = blockIdx.x >> 1;            // 0..79 = b*40+k
  const int k = bk % NBAND_;
  const int b = bk / NBAND_;
  const float a  = tau[k];
  const float om = 1.0f - a;
  const int c  = threadIdx.x >> 5;           // chunk 0..15
  const int pl = threadIdx.x & 31;
  const int p  = ph * 32 + pl;
  const size_t stride = (size_t)NBAND_ * 64;
  size_t idx0 = (size_t)b * (T_ * NBAND_ * 64) + (size_t)(c * 25) * stride + k * 64 + p;

  float y[25];
  float accv = 0.f;
  #pragma unroll
  for (int i = 0; i < 25; i++) {
    float v = z[idx0 + (size_t)i * stride];
    accv = fmaf(a, accv, om * v);
    y[i] = accv;
  }
  gsh[c][pl] = accv;
  __syncthreads();
  float a2 = a * a, a4 = a2 * a2, a8 = a4 * a4, a16 = a8 * a8;
  float A = a16 * a8 * a;                    // a^25
  float H = 0.f;
  #pragma unroll
  for (int d = 0; d < 15; d++) {
    float g = gsh[d][pl];
    H = (d < c) ? fmaf(A, H, g) : H;
  }
  float wp = a;
  #pragma unroll
  for (int i = 0; i < 25; i++) {
    z[idx0 + (size_t)i * stride] = fmaf(wp, H, y[i]);
    wp *= a;
  }
}

extern "C" void kernel_launch(void* const* d_in, const int* in_sizes, int n_in,
                              void* d_out, int out_size, void* d_ws, size_t ws_size,
                              hipStream_t stream)
{
  const float* br   = (const float*)d_in[0];
  const float* bi   = (const float*)d_in[1];
  const float* bmr  = (const float*)d_in[2];
  const float* bmi  = (const float*)d_in[3];
  const float* c2pr = (const float*)d_in[4];
  const float* c2pi = (const float*)d_in[5];
  const float* tau  = (const float*)d_in[6];
  float* out = (float*)d_out;
  float* ws  = (float*)d_ws;

  hipLaunchKernelGGL(pv_prep, dim3(29), dim3(256), 0, stream,
                     bmr, bmi, c2pr, c2pi, ws);
  hipLaunchKernelGGL(pv_main, dim3(B_ * T_), dim3(256), 0, stream,
                     br, bi, ws, out);
  hipLaunchKernelGGL(pv_iir4, dim3(B_ * NBAND_ * 2), dim3(512), 0, stream,
                     out, tau);
}